// Round 4
// baseline (559.728 us; speedup 1.0000x reference)
//
#include <hip/hip_runtime.h>
#include <stdint.h>

// ---------------------------------------------------------------------------
// KnowledgeCircuit: B=4 S=2048 D=1024 N=64 R=128, M = B*S = 8192 tokens.
// Stage 1: h[m,r]   = sum_n w1[m,n] * (x @ F[n])[m,r]        (K=1024 per n)
//   -> z-split over n, scale at epilogue, fp32 atomicAdd into h. Pure GEMM.
// Stage 2: out[m,d] = (g @ Rk_flat)[m,d], g[m,n*128+r] = w2[m,n]*h[m,r]
//   -> expanded-A materialization (134 MB bf16 in ws). Pure GEMM.
// GEMM: 128x128 block, 2x2 waves, 64x64 wave tile (4x4 of 16x16x32 MFMA),
// BK=64, global_load_lds dwordx4 staging, XOR-swizzled LDS (0 conflicts).
// Round-3 lesson: need BOTH fat wave tiles (32 FLOP per LDS byte) AND
// >=3 waves/SIMD -> single accumulator only (no fold).
// ---------------------------------------------------------------------------

typedef unsigned short ushort_t;
typedef __attribute__((ext_vector_type(8))) short frag_t;   // 8 bf16
typedef __attribute__((ext_vector_type(4))) float f32x4;

#define BK 64

__device__ __forceinline__ unsigned short f2bf(float f) {
    unsigned int u = __builtin_bit_cast(unsigned int, f);
    u = (u + 0x7FFFu + ((u >> 16) & 1u)) >> 16;   // RTNE
    return (unsigned short)u;
}

__device__ __forceinline__ void glds16(const ushort_t* g, ushort_t* l) {
    __builtin_amdgcn_global_load_lds(
        (const __attribute__((address_space(1))) unsigned int*)g,
        (__attribute__((address_space(3))) unsigned int*)l,
        16, 0, 0);
}

// ---------------- prepass: fp32 -> bf16 elementwise -------------------------
__global__ __launch_bounds__(256) void convert_bf(const float* __restrict__ in,
                                                  ushort_t* __restrict__ out, int n8) {
    int idx = blockIdx.x * 256 + threadIdx.x;
    if (idx >= n8) return;
    const float4 v0 = ((const float4*)in)[idx * 2];
    const float4 v1 = ((const float4*)in)[idx * 2 + 1];
    unsigned short b[8] = { f2bf(v0.x), f2bf(v0.y), f2bf(v0.z), f2bf(v0.w),
                            f2bf(v1.x), f2bf(v1.y), f2bf(v1.z), f2bf(v1.w) };
    ((uint4*)out)[idx] = *(const uint4*)b;
}

// ---------------- prepass: fp32 RxC -> bf16 CxR transpose -------------------
__global__ __launch_bounds__(256) void transpose_bf(const float* __restrict__ in,
                                                    ushort_t* __restrict__ out,
                                                    int R, int C) {
    __shared__ float tile[64][65];
    const int t  = threadIdx.x;
    const int r0 = blockIdx.x * 64;
    const int c0 = blockIdx.y * 64;
    const int ci = t & 63;
    const int rb = t >> 6;
    #pragma unroll
    for (int p = 0; p < 16; ++p)
        tile[rb + 4 * p][ci] = in[(size_t)(r0 + rb + 4 * p) * C + c0 + ci];
    __syncthreads();
    const int cw = t >> 2;
    const int rg = (t & 3) * 16;
    unsigned short buf[16];
    #pragma unroll
    for (int k = 0; k < 16; ++k)
        buf[k] = f2bf(tile[rg + k][cw]);
    uint4* dst = (uint4*)&out[(size_t)(c0 + cw) * R + r0 + rg];
    dst[0] = *(const uint4*)&buf[0];
    dst[1] = *(const uint4*)&buf[8];
}

// ---------------- prepass: g[m, n*128+r] = bf16(w2[m,n] * h[m,r]) -----------
__global__ __launch_bounds__(256) void make_g(const float* __restrict__ h,
                                              const float* __restrict__ w2,
                                              ushort_t* __restrict__ g) {
    const int idx = blockIdx.x * 256 + threadIdx.x;   // 8,388,608 total
    const int m  = idx >> 10;
    const int c  = idx & 1023;        // 1024 8-elem chunks per row
    const int n  = c >> 4;
    const int r0 = (c & 15) * 8;
    const float w = w2[m * 64 + n];
    const float4 h0 = *(const float4*)(h + (size_t)m * 128 + r0);
    const float4 h1 = *(const float4*)(h + (size_t)m * 128 + r0 + 4);
    unsigned short b[8] = { f2bf(w * h0.x), f2bf(w * h0.y), f2bf(w * h0.z), f2bf(w * h0.w),
                            f2bf(w * h1.x), f2bf(w * h1.y), f2bf(w * h1.z), f2bf(w * h1.w) };
    ((uint4*)g)[idx] = *(const uint4*)b;
}

// ---------------- main GEMM -------------------------------------------------
// C[m,n] (+)= [W[m,z] *] sum_k Ab[m, k] * Bt[n, z*b_seg + k]
// SPLITN=true: z = blockIdx.z selects a B k-segment; epilogue scales by
// W[m,z] and atomicAdds. SPLITN=false: plain GEMM, plain stores.
template<bool SPLITN>
__global__ __launch_bounds__(256, 3)
void kc_gemm(const ushort_t* __restrict__ Ab, const ushort_t* __restrict__ Bt,
             const float* __restrict__ W, float* __restrict__ C,
             int ldA, int ldB, int ldC, int ksteps, int b_seg)
{
    __shared__ ushort_t As[128 * BK];   // 16 KB: 8 chunks(16B)/row, XOR-swizzled
    __shared__ ushort_t Bs[128 * BK];   // 16 KB

    const int t    = threadIdx.x;
    const int lane = t & 63;
    const int wv   = t >> 6;
    const int m0   = blockIdx.x * 128;
    const int n0   = blockIdx.y * 128;
    const int nz   = SPLITN ? blockIdx.z : 0;
    const size_t bko = (size_t)nz * b_seg;

    const int wm = (wv & 1) * 64;
    const int wn = (wv >> 1) * 64;
    const int fr = lane & 15;
    const int q  = lane >> 4;
    const int e  = fr & 7;

    // staging map: deposit d = wv*4+c covers chunk-slots s = d*64+lane;
    // XOR swizzle applied to the GLOBAL source k so chunk lands at slot c^(row&7)
    int srow[4], scol[4];
    #pragma unroll
    for (int c = 0; c < 4; ++c) {
        const int s = (wv * 4 + c) * 64 + lane;
        srow[c] = s >> 3;
        scol[c] = ((s & 7) ^ (srow[c] & 7)) * 8;
    }

    f32x4 acc[4][4];
    #pragma unroll
    for (int i = 0; i < 4; ++i)
        #pragma unroll
        for (int j = 0; j < 4; ++j)
            acc[i][j] = (f32x4){0.f, 0.f, 0.f, 0.f};

    for (int ss = 0; ss < ksteps; ++ss) {
        const int k0 = ss * BK;

        __syncthreads();   // prior frag reads done before overwrite
        #pragma unroll
        for (int c = 0; c < 4; ++c)
            glds16(Ab + (size_t)(m0 + srow[c]) * ldA + k0 + scol[c],
                   &As[(wv * 4 + c) * 512]);
        #pragma unroll
        for (int c = 0; c < 4; ++c)
            glds16(Bt + (size_t)(n0 + srow[c]) * ldB + bko + k0 + scol[c],
                   &Bs[(wv * 4 + c) * 512]);
        __syncthreads();   // drains vmcnt (global_load_lds)

        #pragma unroll
        for (int kk = 0; kk < 2; ++kk) {
            const int csw = (kk * 4 + q) ^ e;
            frag_t a[4], b[4];
            #pragma unroll
            for (int i = 0; i < 4; ++i)
                a[i] = *(const frag_t*)&As[((wm + 16 * i + fr) * 8 + csw) * 8];
            #pragma unroll
            for (int j = 0; j < 4; ++j)
                b[j] = *(const frag_t*)&Bs[((wn + 16 * j + fr) * 8 + csw) * 8];
            #pragma unroll
            for (int i = 0; i < 4; ++i)
                #pragma unroll
                for (int j = 0; j < 4; ++j)
                    acc[i][j] = __builtin_amdgcn_mfma_f32_16x16x32_bf16(
                                    a[i], b[j], acc[i][j], 0, 0, 0);
        }
    }

    // epilogue: C/D layout col=lane&15, row=q*4+reg
    #pragma unroll
    for (int i = 0; i < 4; ++i) {
        #pragma unroll
        for (int r = 0; r < 4; ++r) {
            const int gm = m0 + wm + 16 * i + q * 4 + r;
            if constexpr (SPLITN) {
                const float w = W[(size_t)gm * 64 + nz];
                #pragma unroll
                for (int j = 0; j < 4; ++j)
                    atomicAdd(&C[(size_t)gm * ldC + n0 + wn + 16 * j + fr],
                              w * acc[i][j][r]);
            } else {
                #pragma unroll
                for (int j = 0; j < 4; ++j)
                    C[(size_t)gm * ldC + n0 + wn + 16 * j + fr] = acc[i][j][r];
            }
        }
    }
}

extern "C" void kernel_launch(void* const* d_in, const int* in_sizes, int n_in,
                              void* d_out, int out_size, void* d_ws, size_t ws_size,
                              hipStream_t stream) {
    const float* x  = (const float*)d_in[0];   // [8192, 1024]
    const float* w1 = (const float*)d_in[1];   // [8192, 64]
    const float* w2 = (const float*)d_in[2];   // [8192, 64]
    const float* F  = (const float*)d_in[3];   // (65536, 128) k-major
    const float* Rk = (const float*)d_in[4];   // (8192, 1024) k-major
    float* out = (float*)d_out;                // [8192, 1024]

    char* ws = (char*)d_ws;
    const size_t MB = (size_t)1 << 20;

    if (ws_size >= 148 * MB) {
        // ---- main path: expanded-A stage 2 (148 MB footprint) ----
        float*    h    = (float*)ws;                    // [0,4) MB fp32
        ushort_t* x_bf = (ushort_t*)(ws + 4   * MB);    // [4,20) phase 1
        ushort_t* F_t  = (ushort_t*)(ws + 20  * MB);    // [20,36) phase 1
        ushort_t* g    = (ushort_t*)(ws + 4   * MB);    // [4,132) phase 2 (overlays)
        ushort_t* Rk_t = (ushort_t*)(ws + 132 * MB);    // [132,148)

        hipMemsetAsync(h, 0, 4 * MB, stream);
        convert_bf<<<4096, 256, 0, stream>>>(x, x_bf, 1048576);
        transpose_bf<<<dim3(1024, 2), 256, 0, stream>>>(F, F_t, 65536, 128);
        transpose_bf<<<dim3(128, 16), 256, 0, stream>>>(Rk, Rk_t, 8192, 1024);

        // Stage 1: z=64 over n, K=1024 each, scaled-atomic epilogue into h
        kc_gemm<true><<<dim3(64, 1, 64), 256, 0, stream>>>(
            x_bf, F_t, w1, h, 1024, 65536, 128, 16, 1024);

        // Expand: g[m, n*128+r] = bf16(w2[m,n]*h[m,r])
        make_g<<<32768, 256, 0, stream>>>(h, w2, g);

        // Stage 2: pure GEMM out = g @ Rk_flat  (M=8192 K=8192 N=1024)
        kc_gemm<false><<<dim3(64, 8, 1), 256, 0, stream>>>(
            g, Rk_t, nullptr, out, 8192, 8192, 1024, 128, 0);
    } else {
        // ---- fallback: 38 MB footprint, stage 2 as z=64 atomic split ----
        float*    h    = (float*)ws;                    // [0,4)
        ushort_t* x_bf = (ushort_t*)(ws + 4  * MB);     // [4,20)
        ushort_t* Rk_t = (ushort_t*)(ws + 4  * MB);     // overlays x_bf after stage 1
        ushort_t* F_t  = (ushort_t*)(ws + 20 * MB);     // [20,36)
        ushort_t* h_bf = (ushort_t*)(ws + 36 * MB);     // [36,38)

        hipMemsetAsync(h, 0, 4 * MB, stream);
        hipMemsetAsync(out, 0, (size_t)8192 * 1024 * sizeof(float), stream);
        convert_bf<<<4096, 256, 0, stream>>>(x, x_bf, 1048576);
        transpose_bf<<<dim3(1024, 2), 256, 0, stream>>>(F, F_t, 65536, 128);

        kc_gemm<true><<<dim3(64, 1, 64), 256, 0, stream>>>(
            x_bf, F_t, w1, h, 1024, 65536, 128, 16, 1024);

        convert_bf<<<512, 256, 0, stream>>>(h, h_bf, 131072);
        transpose_bf<<<dim3(128, 16), 256, 0, stream>>>(Rk, Rk_t, 8192, 1024);

        // Stage 2: z=64 over n, K=128 each, scaled-atomic epilogue into out
        kc_gemm<true><<<dim3(64, 8, 64), 256, 0, stream>>>(
            h_bf, Rk_t, w2, out, 128, 8192, 1024, 2, 128);
    }
}

// Round 5
// 456.532 us; speedup vs baseline: 1.2260x; 1.2260x over previous
//
#include <hip/hip_runtime.h>
#include <stdint.h>

// ---------------------------------------------------------------------------
// KnowledgeCircuit: B=4 S=2048 D=1024 N=64 R=128, M = B*S = 8192 tokens.
// Round 5: zero atomics, zero folds.
//   GEMM1: y[m, n*128+r] = sum_d x[m,d] F[n,d,r]     (pure, bf16 out, 128 MiB)
//   mid  : h[m,r] = sum_n w1[m,n] y[m,n*128+r];  y <- g[m,nr] = w2[m,n]h[m,r]
//   GEMM2: out = g @ Rk_flat                         (pure, fp32 out)
// Core: 128x128 block, 2x2 waves, 64x64 wave tile, BK=64, global_load_lds,
// XOR-swizzled LDS (0 conflicts measured). Round-4 lesson: 67M device-scope
// atomicAdds write through to HBM (256 MB WRITE_SIZE) — never again.
// ---------------------------------------------------------------------------

typedef unsigned short ushort_t;
typedef __attribute__((ext_vector_type(8))) short frag_t;   // 8 bf16
typedef __attribute__((ext_vector_type(4))) float f32x4;

#define BK 64

__device__ __forceinline__ unsigned short f2bf(float f) {
    unsigned int u = __builtin_bit_cast(unsigned int, f);
    u = (u + 0x7FFFu + ((u >> 16) & 1u)) >> 16;   // RTNE
    return (unsigned short)u;
}
__device__ __forceinline__ float bf2f_lo(unsigned int v) {
    return __builtin_bit_cast(float, v << 16);
}
__device__ __forceinline__ float bf2f_hi(unsigned int v) {
    return __builtin_bit_cast(float, v & 0xFFFF0000u);
}

__device__ __forceinline__ void glds16(const ushort_t* g, ushort_t* l) {
    __builtin_amdgcn_global_load_lds(
        (const __attribute__((address_space(1))) unsigned int*)g,
        (__attribute__((address_space(3))) unsigned int*)l,
        16, 0, 0);
}

// ---------------- prepass: fp32 -> bf16 elementwise -------------------------
__global__ __launch_bounds__(256) void convert_bf(const float* __restrict__ in,
                                                  ushort_t* __restrict__ out, int n8) {
    int idx = blockIdx.x * 256 + threadIdx.x;
    if (idx >= n8) return;
    const float4 v0 = ((const float4*)in)[idx * 2];
    const float4 v1 = ((const float4*)in)[idx * 2 + 1];
    unsigned short b[8] = { f2bf(v0.x), f2bf(v0.y), f2bf(v0.z), f2bf(v0.w),
                            f2bf(v1.x), f2bf(v1.y), f2bf(v1.z), f2bf(v1.w) };
    ((uint4*)out)[idx] = *(const uint4*)b;
}

// ---------------- prepass: fp32 RxC -> bf16 CxR transpose (batched) ---------
__global__ __launch_bounds__(256) void transpose_bf(const float* __restrict__ in,
                                                    ushort_t* __restrict__ out,
                                                    int R, int C,
                                                    long in_bstride, long out_bstride) {
    __shared__ float tile[64][65];
    in  += (long)blockIdx.z * in_bstride;
    out += (long)blockIdx.z * out_bstride;
    const int t  = threadIdx.x;
    const int r0 = blockIdx.x * 64;
    const int c0 = blockIdx.y * 64;
    const int ci = t & 63;
    const int rb = t >> 6;
    #pragma unroll
    for (int p = 0; p < 16; ++p)
        tile[rb + 4 * p][ci] = in[(size_t)(r0 + rb + 4 * p) * C + c0 + ci];
    __syncthreads();
    const int cw = t >> 2;
    const int rg = (t & 3) * 16;
    unsigned short buf[16];
    #pragma unroll
    for (int k = 0; k < 16; ++k)
        buf[k] = f2bf(tile[rg + k][cw]);
    uint4* dst = (uint4*)&out[(size_t)(c0 + cw) * R + r0 + rg];
    dst[0] = *(const uint4*)&buf[0];
    dst[1] = *(const uint4*)&buf[8];
}

// ---------------- mid: h = w1-reduce(y); y <- g = w2 (x) h (in place) -------
__global__ __launch_bounds__(256) void mid_fuse(ushort_t* __restrict__ y,
                                                const float* __restrict__ w1,
                                                const float* __restrict__ w2) {
    const int m    = blockIdx.x * 4 + (threadIdx.x >> 6);
    const int lane = threadIdx.x & 63;
    unsigned int* yrow = (unsigned int*)(y + (size_t)m * 8192);
    const float* w1r = w1 + (size_t)m * 64;
    const float* w2r = w2 + (size_t)m * 64;
    float h0 = 0.f, h1 = 0.f;
    #pragma unroll 16
    for (int n = 0; n < 64; ++n) {
        const unsigned int v = yrow[n * 64 + lane];
        const float w = w1r[n];
        h0 += w * bf2f_lo(v);
        h1 += w * bf2f_hi(v);
    }
    #pragma unroll 16
    for (int n = 0; n < 64; ++n) {
        const float w = w2r[n];
        yrow[n * 64 + lane] =
            (unsigned int)f2bf(w * h0) | ((unsigned int)f2bf(w * h1) << 16);
    }
}

// ---------------- pure GEMM -------------------------------------------------
// C[m,n] = sum_k Ab[m,k] * Bt[n,k]; 128x128 block, 2x2 waves, 64x64/wave.
template<bool OUT_BF16>
__global__ __launch_bounds__(256, 3)
void kc_gemm(const ushort_t* __restrict__ Ab, const ushort_t* __restrict__ Bt,
             void* __restrict__ Cout, int ldA, int ldB, int ldC, int ksteps)
{
    __shared__ ushort_t As[128 * BK];   // 16 KB: 8 chunks(16B)/row, XOR-swizzled
    __shared__ ushort_t Bs[128 * BK];   // 16 KB

    const int t    = threadIdx.x;
    const int lane = t & 63;
    const int wv   = t >> 6;
    const int m0   = blockIdx.x * 128;
    const int n0   = blockIdx.y * 128;

    const int wm = (wv & 1) * 64;
    const int wn = (wv >> 1) * 64;
    const int fr = lane & 15;
    const int q  = lane >> 4;
    const int e  = fr & 7;

    int srow[4], scol[4];
    #pragma unroll
    for (int c = 0; c < 4; ++c) {
        const int s = (wv * 4 + c) * 64 + lane;
        srow[c] = s >> 3;
        scol[c] = ((s & 7) ^ (srow[c] & 7)) * 8;   // XOR swizzle in global k
    }

    f32x4 acc[4][4];
    #pragma unroll
    for (int i = 0; i < 4; ++i)
        #pragma unroll
        for (int j = 0; j < 4; ++j)
            acc[i][j] = (f32x4){0.f, 0.f, 0.f, 0.f};

    for (int ss = 0; ss < ksteps; ++ss) {
        const int k0 = ss * BK;

        __syncthreads();
        #pragma unroll
        for (int c = 0; c < 4; ++c)
            glds16(Ab + (size_t)(m0 + srow[c]) * ldA + k0 + scol[c],
                   &As[(wv * 4 + c) * 512]);
        #pragma unroll
        for (int c = 0; c < 4; ++c)
            glds16(Bt + (size_t)(n0 + srow[c]) * ldB + k0 + scol[c],
                   &Bs[(wv * 4 + c) * 512]);
        __syncthreads();

        #pragma unroll
        for (int kk = 0; kk < 2; ++kk) {
            const int csw = (kk * 4 + q) ^ e;
            frag_t a[4], b[4];
            #pragma unroll
            for (int i = 0; i < 4; ++i)
                a[i] = *(const frag_t*)&As[((wm + 16 * i + fr) * 8 + csw) * 8];
            #pragma unroll
            for (int j = 0; j < 4; ++j)
                b[j] = *(const frag_t*)&Bs[((wn + 16 * j + fr) * 8 + csw) * 8];
            #pragma unroll
            for (int i = 0; i < 4; ++i)
                #pragma unroll
                for (int j = 0; j < 4; ++j)
                    acc[i][j] = __builtin_amdgcn_mfma_f32_16x16x32_bf16(
                                    a[i], b[j], acc[i][j], 0, 0, 0);
        }
    }

    // epilogue: C/D layout col=lane&15, row=q*4+reg
    #pragma unroll
    for (int i = 0; i < 4; ++i) {
        #pragma unroll
        for (int r = 0; r < 4; ++r) {
            const int gm = m0 + wm + 16 * i + q * 4 + r;
            #pragma unroll
            for (int j = 0; j < 4; ++j) {
                const int gn = n0 + wn + 16 * j + fr;
                if constexpr (OUT_BF16)
                    ((ushort_t*)Cout)[(size_t)gm * ldC + gn] = f2bf(acc[i][j][r]);
                else
                    ((float*)Cout)[(size_t)gm * ldC + gn] = acc[i][j][r];
            }
        }
    }
}

// ---------------- fallback fold-GEMM (round-3, known-good) ------------------
template<int SHIFT, int SEG_STEPS, bool ATOMIC>
__global__ __launch_bounds__(256, 4)
void kc_gemm_fold(const ushort_t* __restrict__ Ab, const float* __restrict__ W,
                  const ushort_t* __restrict__ Bt, float* __restrict__ C,
                  int ldA, int ldB, int ldC, int ksteps)
{
    __shared__ ushort_t As[64 * BK];
    __shared__ ushort_t Bs[128 * BK];
    const int t = threadIdx.x, lane = t & 63, wv = t >> 6;
    const int m0 = blockIdx.x * 64, n0 = blockIdx.y * 128;
    const int kbase = blockIdx.z * ksteps * BK;
    const int wm = (wv & 1) * 32, wn = (wv >> 1) * 64;
    const int fr = lane & 15, q = lane >> 4, e = fr & 7;
    int arow[2], acol[2], brow[4], bcol[4];
    #pragma unroll
    for (int c = 0; c < 2; ++c) {
        const int s = (wv * 2 + c) * 64 + lane;
        arow[c] = s >> 3; acol[c] = ((s & 7) ^ (arow[c] & 7)) * 8;
    }
    #pragma unroll
    for (int c = 0; c < 4; ++c) {
        const int s = (wv * 4 + c) * 64 + lane;
        brow[c] = s >> 3; bcol[c] = ((s & 7) ^ (brow[c] & 7)) * 8;
    }
    f32x4 acc_out[2][4];
    #pragma unroll
    for (int i = 0; i < 2; ++i)
        #pragma unroll
        for (int j = 0; j < 4; ++j) acc_out[i][j] = (f32x4){0.f,0.f,0.f,0.f};
    const int nsegs = ksteps / SEG_STEPS;
    for (int seg = 0; seg < nsegs; ++seg) {
        const int segk = kbase + seg * SEG_STEPS * BK;
        const int nidx = segk >> SHIFT;
        f32x4 acc_in[2][4];
        #pragma unroll
        for (int i = 0; i < 2; ++i)
            #pragma unroll
            for (int j = 0; j < 4; ++j) acc_in[i][j] = (f32x4){0.f,0.f,0.f,0.f};
        for (int ss = 0; ss < SEG_STEPS; ++ss) {
            const int k0 = segk + ss * BK;
            const int d0 = k0 & ((1 << SHIFT) - 1);
            __syncthreads();
            #pragma unroll
            for (int c = 0; c < 2; ++c)
                glds16(Ab + (size_t)(m0 + arow[c]) * ldA + d0 + acol[c],
                       &As[(wv * 2 + c) * 512]);
            #pragma unroll
            for (int c = 0; c < 4; ++c)
                glds16(Bt + (size_t)(n0 + brow[c]) * ldB + k0 + bcol[c],
                       &Bs[(wv * 4 + c) * 512]);
            __syncthreads();
            #pragma unroll
            for (int kk = 0; kk < 2; ++kk) {
                const int csw = (kk * 4 + q) ^ e;
                frag_t a[2], b[4];
                #pragma unroll
                for (int i = 0; i < 2; ++i)
                    a[i] = *(const frag_t*)&As[((wm + 16*i + fr) * 8 + csw) * 8];
                #pragma unroll
                for (int j = 0; j < 4; ++j)
                    b[j] = *(const frag_t*)&Bs[((wn + 16*j + fr) * 8 + csw) * 8];
                #pragma unroll
                for (int i = 0; i < 2; ++i)
                    #pragma unroll
                    for (int j = 0; j < 4; ++j)
                        acc_in[i][j] = __builtin_amdgcn_mfma_f32_16x16x32_bf16(
                                           a[i], b[j], acc_in[i][j], 0, 0, 0);
            }
        }
        #pragma unroll
        for (int i = 0; i < 2; ++i)
            #pragma unroll
            for (int r = 0; r < 4; ++r) {
                const int gm = m0 + wm + 16*i + q*4 + r;
                const float w = W[(size_t)gm * 64 + nidx];
                #pragma unroll
                for (int j = 0; j < 4; ++j) acc_out[i][j][r] += w * acc_in[i][j][r];
            }
    }
    #pragma unroll
    for (int i = 0; i < 2; ++i)
        #pragma unroll
        for (int j = 0; j < 4; ++j)
            #pragma unroll
            for (int r = 0; r < 4; ++r) {
                const int gm = m0 + wm + 16*i + q*4 + r;
                const int gn = n0 + wn + 16*j + fr;
                if constexpr (ATOMIC) atomicAdd(&C[(size_t)gm * ldC + gn], acc_out[i][j][r]);
                else C[(size_t)gm * ldC + gn] = acc_out[i][j][r];
            }
}

extern "C" void kernel_launch(void* const* d_in, const int* in_sizes, int n_in,
                              void* d_out, int out_size, void* d_ws, size_t ws_size,
                              hipStream_t stream) {
    const float* x  = (const float*)d_in[0];   // [8192, 1024]
    const float* w1 = (const float*)d_in[1];   // [8192, 64]
    const float* w2 = (const float*)d_in[2];   // [8192, 64]
    const float* F  = (const float*)d_in[3];   // [64, 1024, 128]
    const float* Rk = (const float*)d_in[4];   // [64, 128, 1024] = (8192, 1024)
    float* out = (float*)d_out;                // [8192, 1024]

    char* ws = (char*)d_ws;
    const size_t MB = (size_t)1 << 20;

    if (ws_size >= 160 * MB) {
        // ---- main path: pure-GEMM pipeline, 160 MiB footprint ----
        ushort_t* y    = (ushort_t*)ws;               // [0,128) MiB: y, then g in place
        ushort_t* x_bf = (ushort_t*)(ws + 128 * MB);  // [128,144)
        ushort_t* F_t2 = (ushort_t*)(ws + 144 * MB);  // [144,160): F_t2[n*128+r, d]
        ushort_t* Rk_t = x_bf;                        // overlays x_bf after GEMM1

        convert_bf<<<4096, 256, 0, stream>>>(x, x_bf, 1048576);
        // per-n transpose: F[n] (1024x128) -> F_t2[n*128 .. n*128+128) x 1024
        transpose_bf<<<dim3(16, 2, 64), 256, 0, stream>>>(
            F, F_t2, 1024, 128, 131072, 131072);

        // GEMM1: y = x_bf @ F_t2^T   (M=8192, N=8192, K=1024), bf16 out
        kc_gemm<true><<<dim3(64, 64), 256, 0, stream>>>(
            x_bf, F_t2, y, 1024, 1024, 8192, 16);

        // mid: h = w1-reduce(y); y <- g = w2 (x) h   (in place)
        mid_fuse<<<2048, 256, 0, stream>>>(y, w1, w2);

        // Rk_t[d, n*128+r] (1024 x 8192), overlays x_bf (dead)
        transpose_bf<<<dim3(128, 16, 1), 256, 0, stream>>>(
            Rk, Rk_t, 8192, 1024, 0, 0);

        // GEMM2: out = g @ Rk_t^T   (M=8192, N=1024, K=8192), fp32 out
        kc_gemm<false><<<dim3(64, 8), 256, 0, stream>>>(
            y, Rk_t, out, 8192, 8192, 1024, 128);
    } else {
        // ---- fallback: round-3 fold pipeline, 38 MiB footprint ----
        float*    h    = (float*)ws;
        ushort_t* x_bf = (ushort_t*)(ws + 4  * MB);
        ushort_t* Rk_t = (ushort_t*)(ws + 4  * MB);   // overlays x_bf after stage 1
        ushort_t* F_t  = (ushort_t*)(ws + 20 * MB);   // F_t[128, 65536]
        ushort_t* h_bf = (ushort_t*)(ws + 36 * MB);

        hipMemsetAsync(h, 0, 4 * MB, stream);
        convert_bf<<<4096, 256, 0, stream>>>(x, x_bf, 1048576);
        transpose_bf<<<dim3(1024, 2, 1), 256, 0, stream>>>(F, F_t, 65536, 128, 0, 0);

        kc_gemm_fold<10, 16, true><<<dim3(128, 1, 8), 256, 0, stream>>>(
            x_bf, w1, F_t, h, 1024, 65536, 128, 128);

        convert_bf<<<512, 256, 0, stream>>>(h, h_bf, 131072);
        transpose_bf<<<dim3(128, 16, 1), 256, 0, stream>>>(Rk, Rk_t, 8192, 1024, 0, 0);

        kc_gemm_fold<7, 2, false><<<dim3(128, 8, 1), 256, 0, stream>>>(
            h_bf, w2, Rk_t, out, 128, 8192, 1024, 128);
    }
}